// Round 3
// baseline (344.523 us; speedup 1.0000x reference)
//
#include <hip/hip_runtime.h>
#include <hip/hip_bf16.h>
#include <math.h>

// MoE top-2 of 8 experts. B=8, C=512, HW=1024, Dh=1024, E=8. fp32 in/out.
// R3: LDS-BW-driven redesign. gemm1 128x256 tile (wave 64x128), gemm2 128x128
// tile BK=64. 64x64 transpose tiles, atomic-free gate partials (aliased in hT).
// Workspace (byte offsets):
//   0      tidx int[16]
//   64     scale fp32[16]
//   32768  xT  bf16 [8][1024 hw][512 c]
//   +8M    W1t bf16 [8][1024 d][512 c]
//   +16M   W2t bf16 [8][512 c][1024 d]
//   +24M   hT  bf16 [8][1024 hw][2048 slotd]   (pp fp32[8][16][512] aliases hT start;
//                                               consumed by gate before gemm1 writes hT)

typedef __bf16 bf16_t;
typedef __attribute__((ext_vector_type(8))) __bf16 bf16x8;
typedef __attribute__((ext_vector_type(4))) __bf16 bf16x4;
typedef __attribute__((ext_vector_type(4))) float f32x4;

#define GLDS(g, l) __builtin_amdgcn_global_load_lds(                      \
    (const __attribute__((address_space(1))) void*)(const void*)(g),       \
    (__attribute__((address_space(3))) void*)(void*)(l), 16, 0, 0)

// erf via Abramowitz-Stegun 7.1.26 (|err|<=1.5e-7 — known-good from R2, absmax 0.031)
__device__ __forceinline__ float gelu_fast(float x) {
    float z = x * 0.70710678118654752f;
    float az = fabsf(z);
    float t = 1.0f / (1.0f + 0.3275911f * az);
    float p = ((((1.061405429f * t - 1.453152027f) * t + 1.421413741f) * t
                - 0.284496736f) * t + 0.254829592f) * t;
    float e = __expf(-az * az);
    float er = copysignf(1.0f - p * e, z);
    return 0.5f * x * (1.0f + er);
}

// ---------- 1. 64x64 transpose+cvt tiles for x/W1/W2 + gate partial sums ----------
__global__ __launch_bounds__(256) void transpose_cvt_all(
    const float* __restrict__ x, const float* __restrict__ W1,
    const float* __restrict__ W2, bf16_t* __restrict__ xT,
    bf16_t* __restrict__ W1t, bf16_t* __restrict__ W2t, float* __restrict__ pp) {
    int id = blockIdx.x;
    const float* src; bf16_t* dst; int Rows, Cols, csh; bool dm = false;
    if (id < 1024)      { src = x;  dst = xT;  Rows = 512;  Cols = 1024; csh = 4; dm = true; }
    else if (id < 2048) { id -= 1024; src = W1; dst = W1t; Rows = 512;  Cols = 1024; csh = 4; }
    else                { id -= 2048; src = W2; dst = W2t; Rows = 1024; Cols = 512; csh = 3; }
    const int bz = id >> 7, t = id & 127;               // 128 tiles per matrix-slice
    const int ct = t & ((1 << csh) - 1), rt = t >> csh;
    const int r0 = rt * 64, c0 = ct * 64;
    __shared__ float tile[64][65];
    const int tid = threadIdx.x;
    const int lr = tid >> 2, ch = tid & 3;
    const float* srow = src + (size_t)bz * Rows * Cols + (size_t)(r0 + lr) * Cols + c0 + ch * 16;
    float4 v0 = ((const float4*)srow)[0];
    float4 v1 = ((const float4*)srow)[1];
    float4 v2 = ((const float4*)srow)[2];
    float4 v3 = ((const float4*)srow)[3];
    float* trow = &tile[lr][ch * 16];
    *(float4*)(trow + 0) = v0; *(float4*)(trow + 4) = v1;
    *(float4*)(trow + 8) = v2; *(float4*)(trow + 12) = v3;
    if (dm) {   // per-(b, hw-tile, c) partial sum -> pp (no atomics: unique writer)
        float s = v0.x + v0.y + v0.z + v0.w + v1.x + v1.y + v1.z + v1.w
                + v2.x + v2.y + v2.z + v2.w + v3.x + v3.y + v3.z + v3.w;
        s += __shfl_down(s, 2, 4);
        s += __shfl_down(s, 1, 4);
        if (ch == 0) pp[(bz * 16 + ct) * 512 + r0 + lr] = s;
    }
    __syncthreads();
    const int oc = tid >> 2;      // output row = source col
    bf16_t ov[16];
    #pragma unroll
    for (int j = 0; j < 16; ++j) ov[j] = (bf16_t)tile[ch * 16 + j][oc];
    bf16_t* drow = dst + (size_t)bz * Rows * Cols + (size_t)(c0 + oc) * Rows + r0 + ch * 16;
    *(bf16x8*)(drow + 0) = *(bf16x8*)&ov[0];
    *(bf16x8*)(drow + 8) = *(bf16x8*)&ov[8];
}

// ---------- 2. gate: reduce pp -> logits -> softmax -> top2 -> scale = w * k[b] ----------
__global__ void gate_kernel(const float* __restrict__ pp, const float* __restrict__ Wg,
                            const float* __restrict__ bg, const float* __restrict__ kmod,
                            int* __restrict__ tidx, float* __restrict__ scale) {
    const int tid = threadIdx.x;           // 512 threads = 8 waves, wave b
    const int b = tid >> 6, l = tid & 63;
    float a[8] = {0.f, 0.f, 0.f, 0.f, 0.f, 0.f, 0.f, 0.f};
    for (int c = l; c < 512; c += 64) {
        float m = 0.f;
        #pragma unroll
        for (int ht = 0; ht < 16; ++ht) m += pp[(b * 16 + ht) * 512 + c];
        #pragma unroll
        for (int e = 0; e < 8; ++e) a[e] += m * Wg[c * 8 + e];
    }
    #pragma unroll
    for (int e = 0; e < 8; ++e)
        #pragma unroll
        for (int off = 32; off; off >>= 1) a[e] += __shfl_xor(a[e], off, 64);
    if (l == 0) {
        float lg[8], mx = -1e30f;
        #pragma unroll
        for (int e = 0; e < 8; ++e) { lg[e] = a[e] * (1.0f / 1024.0f) + bg[e]; mx = fmaxf(mx, lg[e]); }
        float sum = 0.f;
        #pragma unroll
        for (int e = 0; e < 8; ++e) { lg[e] = expf(lg[e] - mx); sum += lg[e]; }
        float inv = 1.0f / sum;
        float best = -1.f; int i0 = 0;
        for (int j = 0; j < 8; ++j) { float w = lg[j] * inv; if (w > best) { best = w; i0 = j; } }
        float best2 = -1.f; int i1 = 0;
        for (int j = 0; j < 8; ++j) { if (j == i0) continue; float w = lg[j] * inv; if (w > best2) { best2 = w; i1 = j; } }
        float kb = kmod[b];
        tidx[b * 2] = i0; tidx[b * 2 + 1] = i1;
        scale[b * 2] = best * kb; scale[b * 2 + 1] = best2 * kb;
    }
}

// ---------- 3. GEMM1: hT[b][hw][slot*1024+d] = bf16(gelu(W1t[e] @ xT[b] + b1)*scale)
// 128(d) x 256(hw) block tile, waves 2x2 of 64x128; BK=32, 16 iters, dbuf single barrier.
__global__ __launch_bounds__(256, 2) void gemm1_kernel(
    const bf16_t* __restrict__ W1t, const bf16_t* __restrict__ xT,
    const float* __restrict__ b1, const int* __restrict__ tidx,
    const float* __restrict__ scale, bf16_t* __restrict__ hT) {
    __shared__ bf16_t smem[24576];   // A stages @0/4096 (128x32), B stages @8192/16384 (256x32)
    const int bid = blockIdx.x;
    const int pair = bid >> 5, rem = bid & 31;   // pair = b*2+slot
    const int b = pair >> 1, slot = pair & 1;
    const int e = tidx[pair];
    const float s = scale[pair];
    const int d0 = (rem >> 2) * 128, n0 = (rem & 3) * 256;
    const int tid = threadIdx.x;
    const int lane = tid & 63, wave = tid >> 6;
    const int wm = (wave & 1) * 64, wn = (wave >> 1) * 128;
    const int lrow = lane & 15, quad = lane >> 4;

    const bf16_t* gA = W1t + (size_t)e * 524288 + (size_t)d0 * 512;
    const bf16_t* gB = xT + (size_t)b * 524288 + (size_t)n0 * 512;
    const int r2 = tid >> 2, kc = (tid & 3) * 8;

    f32x4 acc[4][8];
    #pragma unroll
    for (int i = 0; i < 4; ++i)
        #pragma unroll
        for (int j = 0; j < 8; ++j) acc[i][j] = (f32x4){0.f, 0.f, 0.f, 0.f};

    auto stage = [&](int st, int k0) {
        bf16_t* dA = smem + st * 4096;
        bf16_t* dB = smem + 8192 + st * 8192;
        GLDS(gA + (size_t)r2 * 512 + k0 + kc, dA + tid * 8);
        GLDS(gA + (size_t)(64 + r2) * 512 + k0 + kc, dA + (256 + tid) * 8);
        #pragma unroll
        for (int p = 0; p < 4; ++p)
            GLDS(gB + (size_t)(p * 64 + r2) * 512 + k0 + kc, dB + (p * 256 + tid) * 8);
    };

    stage(0, 0);
    __syncthreads();

    for (int it = 0; it < 16; ++it) {
        const int cur = it & 1;
        if (it < 15) stage(cur ^ 1, (it + 1) * 32);
        const bf16_t* cA = smem + cur * 4096;
        const bf16_t* cB = smem + 8192 + cur * 8192;
        bf16x8 af[4], bfr[8];
        #pragma unroll
        for (int i = 0; i < 4; ++i)
            af[i] = *(const bf16x8*)&cA[(wm + i * 16 + lrow) * 32 + quad * 8];
        #pragma unroll
        for (int j = 0; j < 8; ++j)
            bfr[j] = *(const bf16x8*)&cB[(wn + j * 16 + lrow) * 32 + quad * 8];
        #pragma unroll
        for (int i = 0; i < 4; ++i)
            #pragma unroll
            for (int j = 0; j < 8; ++j)
                acc[i][j] = __builtin_amdgcn_mfma_f32_16x16x32_bf16(af[i], bfr[j], acc[i][j], 0, 0, 0);
        __syncthreads();
    }

    // epilogue: gelu+bias+scale, LDS transpose (64 hw-rows/chunk) -> 16B coalesced stores
    bf16_t* hTb = hT + (size_t)b * 2097152 + slot * 1024;
    float4 bb[4];
    #pragma unroll
    for (int i = 0; i < 4; ++i)
        bb[i] = *(const float4*)(b1 + e * 1024 + d0 + wm + i * 16 + quad * 4);

    for (int chk = 0; chk < 4; ++chk) {      // ebuf: [64 hw][136 d] bf16 in smem
        if ((wn >> 7) == (chk >> 1)) {
            #pragma unroll
            for (int i = 0; i < 4; ++i)
                #pragma unroll
                for (int jj = 0; jj < 4; ++jj) {
                    const int j = (chk & 1) * 4 + jj;
                    const int hw_l = jj * 16 + lrow;
                    const int d_l = wm + i * 16 + quad * 4;
                    f32x4 a = acc[i][j];
                    bf16x4 o = { (bf16_t)(gelu_fast(a[0] + bb[i].x) * s),
                                 (bf16_t)(gelu_fast(a[1] + bb[i].y) * s),
                                 (bf16_t)(gelu_fast(a[2] + bb[i].z) * s),
                                 (bf16_t)(gelu_fast(a[3] + bb[i].w) * s) };
                    *(bf16x4*)&smem[hw_l * 136 + d_l] = o;
                }
        }
        __syncthreads();
        #pragma unroll
        for (int q = 0; q < 4; ++q) {
            const int idx = q * 256 + tid;
            const int row = idx >> 4, c16 = idx & 15;
            bf16x8 v = *(const bf16x8*)&smem[row * 136 + c16 * 8];
            *(bf16x8*)(hTb + (size_t)(n0 + chk * 64 + row) * 2048 + d0 + c16 * 8) = v;
        }
        __syncthreads();
    }
}

// ---------- 4. GEMM2: out = x + W2t(sel) @ hT + scaled b2; 128x128 tile, BK=64, dbuf ----------
__global__ __launch_bounds__(256) void gemm2_kernel(
    const bf16_t* __restrict__ W2t, const bf16_t* __restrict__ hT,
    const float* __restrict__ b2, const int* __restrict__ tidx,
    const float* __restrict__ scale, const float* __restrict__ x,
    float* __restrict__ out) {
    __shared__ bf16_t smem[32768];   // A stages @0/8192 (128x64), B stages @16384/24576
    const int bid = blockIdx.x;
    const int b = bid >> 5, rem = bid & 31;
    const int c0 = (rem >> 3) * 128, n0 = (rem & 7) * 128;
    const int e0 = tidx[b * 2], e1 = tidx[b * 2 + 1];
    const float s0 = scale[b * 2], s1 = scale[b * 2 + 1];
    const int tid = threadIdx.x;
    const int lane = tid & 63, wave = tid >> 6;
    const int wm = (wave & 1) * 64, wn = (wave >> 1) * 64;
    const int lrow = lane & 15, quad = lane >> 4;

    const bf16_t* hTb = hT + (size_t)b * 2097152 + (size_t)n0 * 2048;
    const bf16_t* A0 = W2t + (size_t)e0 * 524288 + (size_t)c0 * 1024;
    const bf16_t* A1 = W2t + (size_t)e1 * 524288 + (size_t)c0 * 1024;
    const int r3 = tid >> 3, kc2 = (tid & 7) * 8;

    f32x4 acc[4][4];
    #pragma unroll
    for (int i = 0; i < 4; ++i)
        #pragma unroll
        for (int j = 0; j < 4; ++j) acc[i][j] = (f32x4){0.f, 0.f, 0.f, 0.f};

    auto stage = [&](int st, int it) {
        const int k0 = it * 64;
        const bf16_t* gA = ((k0 < 1024) ? A0 : A1) + (size_t)r3 * 1024 + (k0 & 1023);
        const bf16_t* gB = hTb + (size_t)r3 * 2048 + k0;
        bf16_t* dA = smem + st * 8192;
        bf16_t* dB = smem + 16384 + st * 8192;
        #pragma unroll
        for (int p = 0; p < 4; ++p) {
            GLDS(gA + (size_t)(p * 32) * 1024 + kc2, dA + (p * 256 + tid) * 8);
            GLDS(gB + (size_t)(p * 32) * 2048 + kc2, dB + (p * 256 + tid) * 8);
        }
    };

    stage(0, 0);
    __syncthreads();

    for (int it = 0; it < 32; ++it) {
        const int cur = it & 1;
        if (it < 31) stage(cur ^ 1, it + 1);
        const bf16_t* cA = smem + cur * 8192;
        const bf16_t* cB = smem + 16384 + cur * 8192;
        #pragma unroll
        for (int kh = 0; kh < 2; ++kh) {
            bf16x8 af[4], bfr[4];
            #pragma unroll
            for (int i = 0; i < 4; ++i) {
                af[i] = *(const bf16x8*)&cA[(wm + i * 16 + lrow) * 64 + kh * 32 + quad * 8];
                bfr[i] = *(const bf16x8*)&cB[(wn + i * 16 + lrow) * 64 + kh * 32 + quad * 8];
            }
            #pragma unroll
            for (int i = 0; i < 4; ++i)
                #pragma unroll
                for (int j = 0; j < 4; ++j)
                    acc[i][j] = __builtin_amdgcn_mfma_f32_16x16x32_bf16(af[i], bfr[j], acc[i][j], 0, 0, 0);
        }
        __syncthreads();
    }

    #pragma unroll
    for (int i = 0; i < 4; ++i) {
        const int c_l = c0 + wm + i * 16 + quad * 4;
        const float4 bA = *(const float4*)(b2 + e0 * 512 + c_l);
        const float4 bB = *(const float4*)(b2 + e1 * 512 + c_l);
        const float bias[4] = { s0 * bA.x + s1 * bB.x, s0 * bA.y + s1 * bB.y,
                                s0 * bA.z + s1 * bB.z, s0 * bA.w + s1 * bB.w };
        #pragma unroll
        for (int j = 0; j < 4; ++j) {
            const int hw = n0 + wn + j * 16 + lrow;
            #pragma unroll
            for (int r = 0; r < 4; ++r) {
                const size_t o = (size_t)(b * 512 + c_l + r) * 1024 + hw;
                out[o] = x[o] + acc[i][j][r] + bias[r];
            }
        }
    }
}

extern "C" void kernel_launch(void* const* d_in, const int* in_sizes, int n_in,
                              void* d_out, int out_size, void* d_ws, size_t ws_size,
                              hipStream_t stream) {
    const float* x    = (const float*)d_in[0];
    const float* kmod = (const float*)d_in[1];
    const float* Wg   = (const float*)d_in[2];
    const float* bg   = (const float*)d_in[3];
    const float* W1   = (const float*)d_in[4];
    const float* b1   = (const float*)d_in[5];
    const float* W2   = (const float*)d_in[6];
    const float* b2   = (const float*)d_in[7];
    float* out = (float*)d_out;

    char* ws = (char*)d_ws;
    int*   tix  = (int*)ws;
    float* scl  = (float*)(ws + 64);
    bf16_t* xT  = (bf16_t*)(ws + 32768);
    bf16_t* W1t = (bf16_t*)(ws + 32768 + (size_t)8388608);
    bf16_t* W2t = (bf16_t*)(ws + 32768 + (size_t)2 * 8388608);
    bf16_t* hT  = (bf16_t*)(ws + 32768 + (size_t)3 * 8388608);
    float* pp   = (float*)hT;   // 256KB gate partials; dead before gemm1 writes hT

    transpose_cvt_all<<<3072, 256, 0, stream>>>(x, W1, W2, xT, W1t, W2t, pp);
    gate_kernel<<<1, 512, 0, stream>>>(pp, Wg, bg, kmod, tix, scl);
    gemm1_kernel<<<512, 256, 0, stream>>>(W1t, xT, b1, tix, scl, hT);
    gemm2_kernel<<<256, 256, 0, stream>>>(W2t, hT, b2, tix, scl, x, out);
}

// Round 5
// 179.799 us; speedup vs baseline: 1.9162x; 1.9162x over previous
//
#include <hip/hip_runtime.h>
#include <hip/hip_bf16.h>
#include <math.h>

// MoE top-2 of 8 experts. B=8, C=512, HW=1024, Dh=1024, E=8. fp32 in/out.
// R5: R4 with the gemm2 grid fixed (1024 blocks, matching b = bid>>7 decode).
// GEMMs are R2-proven structures (static acc indexing — no spill). Coalesced
// 64x64 transpose pass; gate via per-tile partials aliased into hT.
// Workspace (byte offsets):
//   0      tidx int[16]
//   64     scale fp32[16]
//   32768  xT  bf16 [8][1024 hw][512 c]
//   +8M    W1t bf16 [8][1024 d][512 c]
//   +16M   W2t bf16 [8][512 c][1024 d]
//   +24M   hT  bf16 [8][1024 hw][2048 slotd]  (pp fp32[8][16][512] aliases hT;
//                                              consumed by gate before gemm1)

typedef __bf16 bf16_t;
typedef __attribute__((ext_vector_type(8))) __bf16 bf16x8;
typedef __attribute__((ext_vector_type(4))) __bf16 bf16x4;
typedef __attribute__((ext_vector_type(4))) float f32x4;

#define GLDS(g, l) __builtin_amdgcn_global_load_lds(                      \
    (const __attribute__((address_space(1))) void*)(const void*)(g),       \
    (__attribute__((address_space(3))) void*)(void*)(l), 16, 0, 0)

// erf via Abramowitz-Stegun 7.1.26 (|err|<=1.5e-7 — validated R2/R3, absmax 0.031)
__device__ __forceinline__ float gelu_fast(float x) {
    float z = x * 0.70710678118654752f;
    float az = fabsf(z);
    float t = 1.0f / (1.0f + 0.3275911f * az);
    float p = ((((1.061405429f * t - 1.453152027f) * t + 1.421413741f) * t
                - 0.284496736f) * t + 0.254829592f) * t;
    float e = __expf(-az * az);
    float er = copysignf(1.0f - p * e, z);
    return 0.5f * x * (1.0f + er);
}

// ---------- 1. coalesced 64x64 transpose+cvt for x/W1/W2 + gate partials ----------
__global__ __launch_bounds__(256) void transpose_cvt_all(
    const float* __restrict__ x, const float* __restrict__ W1,
    const float* __restrict__ W2, bf16_t* __restrict__ xT,
    bf16_t* __restrict__ W1t, bf16_t* __restrict__ W2t, float* __restrict__ pp) {
    int id = blockIdx.x;
    const float* src; bf16_t* dst; int Rows, Cols, csh; bool dm = false;
    if (id < 1024)      { src = x;  dst = xT;  Rows = 512;  Cols = 1024; csh = 4; dm = true; }
    else if (id < 2048) { id -= 1024; src = W1; dst = W1t; Rows = 512;  Cols = 1024; csh = 4; }
    else                { id -= 2048; src = W2; dst = W2t; Rows = 1024; Cols = 512; csh = 3; }
    const int bz = id >> 7, t = id & 127;
    const int ct = t & ((1 << csh) - 1), rt = t >> csh;
    const int r0 = rt * 64, c0 = ct * 64;
    __shared__ float tile[64][65];
    const int tid = threadIdx.x;
    const int lrw = tid >> 4, lcol = (tid & 15) * 4;
    const float* sb = src + (size_t)bz * Rows * Cols + c0;
    #pragma unroll
    for (int p = 0; p < 4; ++p) {
        const int row = p * 16 + lrw;
        float4 v = *(const float4*)(sb + (size_t)(r0 + row) * Cols + lcol);
        tile[row][lcol + 0] = v.x; tile[row][lcol + 1] = v.y;
        tile[row][lcol + 2] = v.z; tile[row][lcol + 3] = v.w;
    }
    __syncthreads();
    if (dm) {   // per-(b, hw-tile, c-row) partial sums for the gate (unique writer)
        const int row = tid >> 2, q = tid & 3;
        float s = 0.f;
        #pragma unroll
        for (int j = 0; j < 16; ++j) s += tile[row][q * 16 + j];
        s += __shfl_down(s, 2, 4);
        s += __shfl_down(s, 1, 4);
        if (q == 0) pp[(bz * 16 + ct) * 512 + r0 + row] = s;
    }
    bf16_t* db = dst + (size_t)bz * Rows * Cols + r0;
    #pragma unroll
    for (int q = 0; q < 2; ++q) {
        const int idq = q * 256 + tid;
        const int orow = idq >> 3, seg = idq & 7;
        bf16_t ov[8];
        #pragma unroll
        for (int j = 0; j < 8; ++j) ov[j] = (bf16_t)tile[seg * 8 + j][orow];
        *(bf16x8*)(db + (size_t)(c0 + orow) * Rows + seg * 8) = *(bf16x8*)ov;
    }
}

// ---------- 2. gate: reduce pp -> logits -> softmax -> top2 -> scale = w * k[b] ----------
__global__ void gate_kernel(const float* __restrict__ pp, const float* __restrict__ Wg,
                            const float* __restrict__ bg, const float* __restrict__ kmod,
                            int* __restrict__ tidx, float* __restrict__ scale) {
    const int tid = threadIdx.x;           // 512 threads = 8 waves, wave b
    const int b = tid >> 6, l = tid & 63;
    float a[8] = {0.f, 0.f, 0.f, 0.f, 0.f, 0.f, 0.f, 0.f};
    for (int c = l; c < 512; c += 64) {
        float m = 0.f;
        #pragma unroll
        for (int ht = 0; ht < 16; ++ht) m += pp[(b * 16 + ht) * 512 + c];
        #pragma unroll
        for (int e = 0; e < 8; ++e) a[e] += m * Wg[c * 8 + e];
    }
    #pragma unroll
    for (int e = 0; e < 8; ++e)
        #pragma unroll
        for (int off = 32; off; off >>= 1) a[e] += __shfl_xor(a[e], off, 64);
    if (l == 0) {
        float lg[8], mx = -1e30f;
        #pragma unroll
        for (int e = 0; e < 8; ++e) { lg[e] = a[e] * (1.0f / 1024.0f) + bg[e]; mx = fmaxf(mx, lg[e]); }
        float sum = 0.f;
        #pragma unroll
        for (int e = 0; e < 8; ++e) { lg[e] = expf(lg[e] - mx); sum += lg[e]; }
        float inv = 1.0f / sum;
        float best = -1.f; int i0 = 0;
        for (int j = 0; j < 8; ++j) { float w = lg[j] * inv; if (w > best) { best = w; i0 = j; } }
        float best2 = -1.f; int i1 = 0;
        for (int j = 0; j < 8; ++j) { if (j == i0) continue; float w = lg[j] * inv; if (w > best2) { best2 = w; i1 = j; } }
        float kb = kmod[b];
        tidx[b * 2] = i0; tidx[b * 2 + 1] = i1;
        scale[b * 2] = best * kb; scale[b * 2 + 1] = best2 * kb;
    }
}

// ---------- 3. GEMM1 (R2-proven): hT = bf16(gelu(W1t[e] @ xT[b] + b1)*scale)
// 128x128 tile, BK=32, single-barrier dbuf, LDS-transposed coalesced epilogue.
__global__ __launch_bounds__(256, 4) void gemm1_kernel(
    const bf16_t* __restrict__ W1t, const bf16_t* __restrict__ xT,
    const float* __restrict__ b1, const int* __restrict__ tidx,
    const float* __restrict__ scale, bf16_t* __restrict__ hT) {
    __shared__ bf16_t smem[16384];   // A stages @0/4096, B stages @8192/12288
    const int bid = blockIdx.x;
    const int pair = bid >> 6, rem = bid & 63;
    const int b = pair >> 1, slot = pair & 1;
    const int e = tidx[pair];
    const float s = scale[pair];
    const int d0 = (rem >> 3) * 128, n0 = (rem & 7) * 128;
    const int tid = threadIdx.x;
    const int lane = tid & 63, wave = tid >> 6;
    const int wm = (wave & 1) * 64, wn = (wave >> 1) * 64;
    const int lrow = lane & 15, quad = lane >> 4;

    const bf16_t* gA = W1t + (size_t)e * 524288 + (size_t)d0 * 512;
    const bf16_t* gB = xT + (size_t)b * 524288 + (size_t)n0 * 512;
    const int r0s = tid >> 2, kcs = (tid & 3) * 8;

    f32x4 acc[4][4];
    #pragma unroll
    for (int i = 0; i < 4; ++i)
        #pragma unroll
        for (int j = 0; j < 4; ++j) acc[i][j] = (f32x4){0.f, 0.f, 0.f, 0.f};

    GLDS(gA + r0s * 512 + kcs, smem + tid * 8);
    GLDS(gA + (64 + r0s) * 512 + kcs, smem + (256 + tid) * 8);
    GLDS(gB + r0s * 512 + kcs, smem + 8192 + tid * 8);
    GLDS(gB + (64 + r0s) * 512 + kcs, smem + 8192 + (256 + tid) * 8);
    __syncthreads();

    for (int it = 0; it < 16; ++it) {
        const int cur = it & 1;
        if (it < 15) {
            const int kn = (it + 1) * 32;
            bf16_t* dA = smem + (cur ^ 1) * 4096;
            bf16_t* dB = smem + 8192 + (cur ^ 1) * 4096;
            GLDS(gA + r0s * 512 + kn + kcs, dA + tid * 8);
            GLDS(gA + (64 + r0s) * 512 + kn + kcs, dA + (256 + tid) * 8);
            GLDS(gB + r0s * 512 + kn + kcs, dB + tid * 8);
            GLDS(gB + (64 + r0s) * 512 + kn + kcs, dB + (256 + tid) * 8);
        }
        const bf16_t* cA = smem + cur * 4096;
        const bf16_t* cB = smem + 8192 + cur * 4096;
        bf16x8 af[4], bfr[4];
        #pragma unroll
        for (int i = 0; i < 4; ++i) {
            af[i] = *(const bf16x8*)&cA[(wm + i * 16 + lrow) * 32 + quad * 8];
            bfr[i] = *(const bf16x8*)&cB[(wn + i * 16 + lrow) * 32 + quad * 8];
        }
        #pragma unroll
        for (int i = 0; i < 4; ++i)
            #pragma unroll
            for (int j = 0; j < 4; ++j)
                acc[i][j] = __builtin_amdgcn_mfma_f32_16x16x32_bf16(af[i], bfr[j], acc[i][j], 0, 0, 0);
        __syncthreads();
    }

    bf16_t* hTb = hT + (size_t)b * 2097152 + slot * 1024;
    float4 bb[4];
    #pragma unroll
    for (int i = 0; i < 4; ++i)
        bb[i] = *(const float4*)(b1 + e * 1024 + d0 + wm + i * 16 + quad * 4);

    #pragma unroll
    for (int half = 0; half < 2; ++half) {   // ebuf: [64 hw][136 d] bf16
        if (wn == half * 64) {
            #pragma unroll
            for (int i = 0; i < 4; ++i)
                #pragma unroll
                for (int j = 0; j < 4; ++j) {
                    const int hw_l = j * 16 + lrow;
                    const int d_l = wm + i * 16 + quad * 4;
                    f32x4 a = acc[i][j];
                    bf16x4 o = { (bf16_t)(gelu_fast(a[0] + bb[i].x) * s),
                                 (bf16_t)(gelu_fast(a[1] + bb[i].y) * s),
                                 (bf16_t)(gelu_fast(a[2] + bb[i].z) * s),
                                 (bf16_t)(gelu_fast(a[3] + bb[i].w) * s) };
                    *(bf16x4*)&smem[hw_l * 136 + d_l] = o;
                }
        }
        __syncthreads();
        #pragma unroll
        for (int q = 0; q < 4; ++q) {
            const int cid = q * 256 + tid;
            const int row = cid >> 4, c16 = cid & 15;
            bf16x8 v = *(const bf16x8*)&smem[row * 136 + c16 * 8];
            *(bf16x8*)(hTb + (size_t)(n0 + half * 64 + row) * 2048 + d0 + c16 * 8) = v;
        }
        __syncthreads();
    }
}

// ---------- 4. GEMM2 (R2-proven): out = x + W2t(sel) @ hT + scaled b2; 64x64, BK=64 ----------
__global__ __launch_bounds__(256, 5) void gemm2_kernel(
    const bf16_t* __restrict__ W2t, const bf16_t* __restrict__ hT,
    const float* __restrict__ b2, const int* __restrict__ tidx,
    const float* __restrict__ scale, const float* __restrict__ x,
    float* __restrict__ out) {
    __shared__ bf16_t smem[16384];   // A stages @0/4096 (2 panels 64x32), B @8192/12288
    const int bid = blockIdx.x;
    const int b = bid >> 7, rem = bid & 127;     // grid MUST be 1024 (8*128)
    const int c0 = (rem >> 4) * 64, n0 = (rem & 15) * 64;
    const int e0 = tidx[b * 2], e1 = tidx[b * 2 + 1];
    const float s0 = scale[b * 2], s1 = scale[b * 2 + 1];
    const int tid = threadIdx.x;
    const int lane = tid & 63, wave = tid >> 6;
    const int wm = (wave & 1) * 32, wn = (wave >> 1) * 32;
    const int lrow = lane & 15, quad = lane >> 4;

    const bf16_t* hTb = hT + (size_t)b * 2097152 + (size_t)n0 * 2048;
    const bf16_t* A0 = W2t + (size_t)e0 * 524288 + (size_t)c0 * 1024;
    const bf16_t* A1 = W2t + (size_t)e1 * 524288 + (size_t)c0 * 1024;
    const int sr = tid >> 2, kcs = (tid & 3) * 8;

    f32x4 acc[2][2];
    #pragma unroll
    for (int i = 0; i < 2; ++i)
        #pragma unroll
        for (int j = 0; j < 2; ++j) acc[i][j] = (f32x4){0.f, 0.f, 0.f, 0.f};

    auto stage = [&](int st, int it) {
        const int k0 = it * 64;
        const bf16_t* gA = ((k0 < 1024) ? A0 : A1) + (size_t)sr * 1024 + (k0 & 1023);
        bf16_t* dA = smem + st * 4096;
        bf16_t* dB = smem + 8192 + st * 4096;
        GLDS(gA + kcs, dA + tid * 8);
        GLDS(gA + 32 + kcs, dA + 2048 + tid * 8);
        const bf16_t* gBp = hTb + (size_t)sr * 2048 + k0;
        GLDS(gBp + kcs, dB + tid * 8);
        GLDS(gBp + 32 + kcs, dB + 2048 + tid * 8);
    };

    stage(0, 0);
    __syncthreads();

    for (int it = 0; it < 32; ++it) {
        const int cur = it & 1;
        if (it < 31) stage(cur ^ 1, it + 1);
        const bf16_t* cA = smem + cur * 4096;
        const bf16_t* cB = smem + 8192 + cur * 4096;
        #pragma unroll
        for (int ks = 0; ks < 2; ++ks) {
            bf16x8 af[2], bfr[2];
            #pragma unroll
            for (int i = 0; i < 2; ++i) {
                af[i] = *(const bf16x8*)&cA[ks * 2048 + (wm + i * 16 + lrow) * 32 + quad * 8];
                bfr[i] = *(const bf16x8*)&cB[ks * 2048 + (wn + i * 16 + lrow) * 32 + quad * 8];
            }
            #pragma unroll
            for (int i = 0; i < 2; ++i)
                #pragma unroll
                for (int j = 0; j < 2; ++j)
                    acc[i][j] = __builtin_amdgcn_mfma_f32_16x16x32_bf16(af[i], bfr[j], acc[i][j], 0, 0, 0);
        }
        __syncthreads();
    }

    #pragma unroll
    for (int i = 0; i < 2; ++i) {
        const int c_l = c0 + wm + i * 16 + quad * 4;
        const float4 bA = *(const float4*)(b2 + e0 * 512 + c_l);
        const float4 bB = *(const float4*)(b2 + e1 * 512 + c_l);
        const float bias[4] = { s0 * bA.x + s1 * bB.x, s0 * bA.y + s1 * bB.y,
                                s0 * bA.z + s1 * bB.z, s0 * bA.w + s1 * bB.w };
        #pragma unroll
        for (int j = 0; j < 2; ++j) {
            const int hw = n0 + wn + j * 16 + lrow;
            #pragma unroll
            for (int r = 0; r < 4; ++r) {
                const size_t o = (size_t)(b * 512 + c_l + r) * 1024 + hw;
                out[o] = x[o] + acc[i][j][r] + bias[r];
            }
        }
    }
}

extern "C" void kernel_launch(void* const* d_in, const int* in_sizes, int n_in,
                              void* d_out, int out_size, void* d_ws, size_t ws_size,
                              hipStream_t stream) {
    const float* x    = (const float*)d_in[0];
    const float* kmod = (const float*)d_in[1];
    const float* Wg   = (const float*)d_in[2];
    const float* bg   = (const float*)d_in[3];
    const float* W1   = (const float*)d_in[4];
    const float* b1   = (const float*)d_in[5];
    const float* W2   = (const float*)d_in[6];
    const float* b2   = (const float*)d_in[7];
    float* out = (float*)d_out;

    char* ws = (char*)d_ws;
    int*   tix  = (int*)ws;
    float* scl  = (float*)(ws + 64);
    bf16_t* xT  = (bf16_t*)(ws + 32768);
    bf16_t* W1t = (bf16_t*)(ws + 32768 + (size_t)8388608);
    bf16_t* W2t = (bf16_t*)(ws + 32768 + (size_t)2 * 8388608);
    bf16_t* hT  = (bf16_t*)(ws + 32768 + (size_t)3 * 8388608);
    float* pp   = (float*)hT;   // 256KB gate partials; dead before gemm1 writes hT

    transpose_cvt_all<<<3072, 256, 0, stream>>>(x, W1, W2, xT, W1t, W2t, pp);
    gate_kernel<<<1, 512, 0, stream>>>(pp, Wg, bg, kmod, tix, scl);
    gemm1_kernel<<<1024, 256, 0, stream>>>(W1t, xT, b1, tix, scl, hT);
    gemm2_kernel<<<1024, 256, 0, stream>>>(W2t, hT, b2, tix, scl, x, out);   // grid = 8*128
}